// Round 7
// baseline (20167.889 us; speedup 1.0000x reference)
//
#include <hip/hip_runtime.h>
#include <math.h>

#define T_STEPS 2048
#define BATCH   64
#define HDIM    512
#define GDIM    2048   // 4*H
#define INDIM   256
#define NBLK_RE 128    // recurrence workgroups PER LAYER (1 per 4 h-dims)
#define HB_STEP (HDIM * BATCH)   // elements per timestep slot

typedef _Float16 f16x8 __attribute__((ext_vector_type(8)));
typedef _Float16 f16x4 __attribute__((ext_vector_type(4)));
typedef float    f32x4 __attribute__((ext_vector_type(4)));

__device__ __forceinline__ float sigf(float x) { return 1.0f / (1.0f + __expf(-x)); }
__device__ __forceinline__ float tanh_fast(float x) {
    return 1.0f - 2.0f / (__expf(2.0f * x) + 1.0f);   // saturates correctly
}

// ---------------------------------------------------------------------------
// fp32 -> fp16 conversion (weights once per launch; x once, 67 MB)
// ---------------------------------------------------------------------------
__global__ __launch_bounds__(256) void cvt_f16(const float* __restrict__ src,
                                               _Float16* __restrict__ dst, int n4)
{
    int i = blockIdx.x * 256 + threadIdx.x;
    if (i < n4) {
        float4 v = ((const float4*)src)[i];
        f16x4 h;
        h[0] = (_Float16)v.x; h[1] = (_Float16)v.y;
        h[2] = (_Float16)v.z; h[3] = (_Float16)v.w;
        ((f16x4*)dst)[i] = h;
    }
}

// ---------------------------------------------------------------------------
// R1-proven single-counter barrier. Producers: one fetch_add per WG (LLC
// atomic units pipeline same-address RMWs, ~0.3us for 128). Consumers: spin
// on ONE relaxed agent load (wave-uniform address -> 1 load/wave/iter; one
// hot line broadcasts cheaply to all XCDs). Flag-array variants (R2-R6,
// 128 distinct lines) all measured SLOWER: exit is gated by the slowest
// line's propagation, and R6's packed lines added producer-side contention.
// Absolute targets (128*t) -> no per-chunk reset.
// ---------------------------------------------------------------------------
__device__ __forceinline__ void wait_ctr(const unsigned* __restrict__ ctr,
                                         unsigned tgt)
{
    while (__hip_atomic_load(ctr, __ATOMIC_RELAXED, __HIP_MEMORY_SCOPE_AGENT) < tgt) {}
    __atomic_signal_fence(__ATOMIC_ACQUIRE);
}

// ---------------------------------------------------------------------------
// Fully-fused 2-layer MFMA LSTM. 256 WGs: blocks 0..127 = layer 1 (x GEMM
// folded, K=256 fp16), 128..255 = layer 2 (W_ih2@h1 folded, K=512).
// h buffers BATCH-MAJOR [t][b][512]; packed 8B publish via hsm + wave 0
// (round-4 proven). Split MFMA accumulators (round-5). Single-counter
// barrier (round-1 proven, reverted after flag-array detour R2-R6).
// ---------------------------------------------------------------------------
__global__ __launch_bounds__(256, 1) void lstm_fused(
    const _Float16* __restrict__ xh,     // [nsteps][64][256] fp16 (batch-major)
    const _Float16* __restrict__ Wf1h,   // W_hh1 [2048][512]
    const _Float16* __restrict__ Wf1i,   // W_ih1 [2048][256]
    const _Float16* __restrict__ Wf2i,   // W_ih2 [2048][512]
    const _Float16* __restrict__ Wf2h,   // W_hh2 [2048][512]
    const float* __restrict__ bih1, const float* __restrict__ bhh1,
    const float* __restrict__ bih2, const float* __restrict__ bhh2,
    _Float16* __restrict__ hb1,          // [nsteps+1][64][512] batch-major
    _Float16* __restrict__ hb2,
    float* __restrict__ c1,              // [512][64]
    float* __restrict__ c2,
    unsigned* __restrict__ ctr1,         // single counter, own 128B line
    unsigned* __restrict__ ctr2,
    int nsteps, unsigned t0a)
{
    __shared__ float    gl[16][68];      // gate exchange, padded
    __shared__ _Float16 hsm[64][4];      // packed h per batch

    const int tid   = threadIdx.x;
    const int layer = blockIdx.x >> 7;
    const int wg    = blockIdx.x & (NBLK_RE - 1);
    const int j0    = wg * 4;
    const int wv    = tid >> 6;          // wave = M-tile (16 batches)
    const int ln    = tid & 63;
    const int l16   = ln & 15;
    const int quad  = ln >> 4;
    const int grow  = (l16 >> 2) * HDIM + j0 + (l16 & 3);
    const int du    = wv;                // update thread: dim j0+du, batch bu
    const int bu    = tid & 63;
    const int dd    = j0 + du;

    if (layer == 0) {
        // ------------------------- layer 1 -------------------------
        f16x8 Bh[16], Bx[8];
#pragma unroll
        for (int j = 0; j < 16; j++) {
            const uint4 u = *(const uint4*)&Wf1h[(size_t)grow * HDIM + j * 32 + quad * 8];
            Bh[j] = __builtin_bit_cast(f16x8, u);
        }
#pragma unroll
        for (int j = 0; j < 8; j++) {
            const uint4 u = *(const uint4*)&Wf1i[(size_t)grow * INDIM + j * 32 + quad * 8];
            Bx[j] = __builtin_bit_cast(f16x8, u);
        }
        float c_reg = c1[(size_t)dd * BATCH + bu];
        const float bi_ = bih1[0 * HDIM + dd] + bhh1[0 * HDIM + dd];
        const float bf_ = bih1[1 * HDIM + dd] + bhh1[1 * HDIM + dd];
        const float bg_ = bih1[2 * HDIM + dd] + bhh1[2 * HDIM + dd];
        const float bo_ = bih1[3 * HDIM + dd] + bhh1[3 * HDIM + dd];

        for (int t = 0; t < nsteps; t++) {
            f32x4 ax0 = {0.f, 0.f, 0.f, 0.f}, ax1 = {0.f, 0.f, 0.f, 0.f};

            // --- x contribution first (independent accumulators; no dep) ---
            {
                const _Float16* xp = xh + ((size_t)t * BATCH + 16 * wv + l16) * INDIM
                                   + quad * 8;
                ulonglong2 ax[8];
#pragma unroll
                for (int j = 0; j < 8; j++)
                    ax[j] = *(const ulonglong2*)(xp + j * 32);
#pragma unroll
                for (int j = 0; j < 8; j += 2) {
                    ax0 = __builtin_amdgcn_mfma_f32_16x16x32_f16(
                        __builtin_bit_cast(f16x8, ax[j]),     Bx[j],     ax0, 0, 0, 0);
                    ax1 = __builtin_amdgcn_mfma_f32_16x16x32_f16(
                        __builtin_bit_cast(f16x8, ax[j + 1]), Bx[j + 1], ax1, 0, 0, 0);
                }
            }

            // --- critical path: W_hh1 @ h1[t] (fresh accumulator chains) ---
            wait_ctr(ctr1, (unsigned)NBLK_RE * (t0a + (unsigned)t));
            f32x4 ah0 = {0.f, 0.f, 0.f, 0.f}, ah1 = {0.f, 0.f, 0.f, 0.f};
            f32x4 ah2 = {0.f, 0.f, 0.f, 0.f}, ah3 = {0.f, 0.f, 0.f, 0.f};
            {
                const _Float16* hp = hb1 + (size_t)t * HB_STEP
                                   + (size_t)(16 * wv + l16) * HDIM + quad * 8;
                ulonglong2 a[16];
#pragma unroll
                for (int j = 0; j < 16; j++)
                    a[j] = *(const ulonglong2*)(hp + j * 32);
#pragma unroll
                for (int j = 0; j < 16; j += 4) {
                    ah0 = __builtin_amdgcn_mfma_f32_16x16x32_f16(
                        __builtin_bit_cast(f16x8, a[j]),     Bh[j],     ah0, 0, 0, 0);
                    ah1 = __builtin_amdgcn_mfma_f32_16x16x32_f16(
                        __builtin_bit_cast(f16x8, a[j + 1]), Bh[j + 1], ah1, 0, 0, 0);
                    ah2 = __builtin_amdgcn_mfma_f32_16x16x32_f16(
                        __builtin_bit_cast(f16x8, a[j + 2]), Bh[j + 2], ah2, 0, 0, 0);
                    ah3 = __builtin_amdgcn_mfma_f32_16x16x32_f16(
                        __builtin_bit_cast(f16x8, a[j + 3]), Bh[j + 3], ah3, 0, 0, 0);
                }
            }
            f32x4 d = (ax0 + ax1) + ((ah0 + ah1) + (ah2 + ah3));
            *(f32x4*)&gl[l16][16 * wv + quad * 4] = d;
            __syncthreads();

            {
                float si = gl[4 * 0 + du][bu] + bi_;
                float sf = gl[4 * 1 + du][bu] + bf_;
                float sg = gl[4 * 2 + du][bu] + bg_;
                float so = gl[4 * 3 + du][bu] + bo_;
                c_reg = sigf(sf) * c_reg + sigf(si) * tanh_fast(sg);
                float h = sigf(so) * tanh_fast(c_reg);
                hsm[bu][du] = (_Float16)h;
            }
            __syncthreads();   // hsm ready; also protects gl before next D-write

            // --- packed publish (wave 0): one 8B quad per batch ---
            if (tid < 64) {
                unsigned long long pk = *(const unsigned long long*)&hsm[tid][0];
                unsigned long long* dst = (unsigned long long*)
                    (hb1 + (size_t)(t + 1) * HB_STEP + (size_t)tid * HDIM + j0);
                __hip_atomic_store(dst, pk, __ATOMIC_RELAXED, __HIP_MEMORY_SCOPE_AGENT);
                if (t == nsteps - 1) {   // carry slot for next chunk
                    unsigned long long* dst0 = (unsigned long long*)
                        (hb1 + (size_t)tid * HDIM + j0);
                    __hip_atomic_store(dst0, pk, __ATOMIC_RELAXED, __HIP_MEMORY_SCOPE_AGENT);
                }
                if (tid == 0) {
                    asm volatile("s_waitcnt vmcnt(0)" ::: "memory");  // h at LLC
                    __hip_atomic_fetch_add(ctr1, 1u, __ATOMIC_RELAXED,
                                           __HIP_MEMORY_SCOPE_AGENT);
                }
            }
        }
        c1[(size_t)dd * BATCH + bu] = c_reg;
    } else {
        // ------------------------- layer 2 -------------------------
        f16x8 Bh[16], Bi[16];
#pragma unroll
        for (int j = 0; j < 16; j++) {
            const uint4 uh = *(const uint4*)&Wf2h[(size_t)grow * HDIM + j * 32 + quad * 8];
            Bh[j] = __builtin_bit_cast(f16x8, uh);
            const uint4 ui = *(const uint4*)&Wf2i[(size_t)grow * HDIM + j * 32 + quad * 8];
            Bi[j] = __builtin_bit_cast(f16x8, ui);
        }
        float c_reg = c2[(size_t)dd * BATCH + bu];
        const float bi_ = bih2[0 * HDIM + dd] + bhh2[0 * HDIM + dd];
        const float bf_ = bih2[1 * HDIM + dd] + bhh2[1 * HDIM + dd];
        const float bg_ = bih2[2 * HDIM + dd] + bhh2[2 * HDIM + dd];
        const float bo_ = bih2[3 * HDIM + dd] + bhh2[3 * HDIM + dd];

        for (int t = 0; t < nsteps; t++) {
            f32x4 ai0 = {0.f, 0.f, 0.f, 0.f}, ai1 = {0.f, 0.f, 0.f, 0.f};
            f32x4 ag0 = {0.f, 0.f, 0.f, 0.f}, ag1 = {0.f, 0.f, 0.f, 0.f};

            // --- W_ih2 @ h1[t+1] (independent accumulators) ---
            wait_ctr(ctr1, (unsigned)NBLK_RE * (t0a + (unsigned)t + 1u));
            {
                const _Float16* hp = hb1 + (size_t)(t + 1) * HB_STEP
                                   + (size_t)(16 * wv + l16) * HDIM + quad * 8;
                ulonglong2 a[16];
#pragma unroll
                for (int j = 0; j < 16; j++)
                    a[j] = *(const ulonglong2*)(hp + j * 32);
#pragma unroll
                for (int j = 0; j < 16; j += 2) {
                    ai0 = __builtin_amdgcn_mfma_f32_16x16x32_f16(
                        __builtin_bit_cast(f16x8, a[j]),     Bi[j],     ai0, 0, 0, 0);
                    ai1 = __builtin_amdgcn_mfma_f32_16x16x32_f16(
                        __builtin_bit_cast(f16x8, a[j + 1]), Bi[j + 1], ai1, 0, 0, 0);
                }
            }

            // --- critical path: W_hh2 @ h2[t] ---
            wait_ctr(ctr2, (unsigned)NBLK_RE * (t0a + (unsigned)t));
            {
                const _Float16* hp = hb2 + (size_t)t * HB_STEP
                                   + (size_t)(16 * wv + l16) * HDIM + quad * 8;
                ulonglong2 a[16];
#pragma unroll
                for (int j = 0; j < 16; j++)
                    a[j] = *(const ulonglong2*)(hp + j * 32);
#pragma unroll
                for (int j = 0; j < 16; j += 2) {
                    ag0 = __builtin_amdgcn_mfma_f32_16x16x32_f16(
                        __builtin_bit_cast(f16x8, a[j]),     Bh[j],     ag0, 0, 0, 0);
                    ag1 = __builtin_amdgcn_mfma_f32_16x16x32_f16(
                        __builtin_bit_cast(f16x8, a[j + 1]), Bh[j + 1], ag1, 0, 0, 0);
                }
            }
            f32x4 d = (ai0 + ai1) + (ag0 + ag1);
            *(f32x4*)&gl[l16][16 * wv + quad * 4] = d;
            __syncthreads();

            {
                float si = gl[4 * 0 + du][bu] + bi_;
                float sf = gl[4 * 1 + du][bu] + bf_;
                float sg = gl[4 * 2 + du][bu] + bg_;
                float so = gl[4 * 3 + du][bu] + bo_;
                c_reg = sigf(sf) * c_reg + sigf(si) * tanh_fast(sg);
                float h = sigf(so) * tanh_fast(c_reg);
                hsm[bu][du] = (_Float16)h;
            }
            __syncthreads();

            if (tid < 64) {
                unsigned long long pk = *(const unsigned long long*)&hsm[tid][0];
                unsigned long long* dst = (unsigned long long*)
                    (hb2 + (size_t)(t + 1) * HB_STEP + (size_t)tid * HDIM + j0);
                __hip_atomic_store(dst, pk, __ATOMIC_RELAXED, __HIP_MEMORY_SCOPE_AGENT);
                if (t == nsteps - 1) {
                    unsigned long long* dst0 = (unsigned long long*)
                        (hb2 + (size_t)tid * HDIM + j0);
                    __hip_atomic_store(dst0, pk, __ATOMIC_RELAXED, __HIP_MEMORY_SCOPE_AGENT);
                }
                if (tid == 0) {
                    asm volatile("s_waitcnt vmcnt(0)" ::: "memory");
                    __hip_atomic_fetch_add(ctr2, 1u, __ATOMIC_RELAXED,
                                           __HIP_MEMORY_SCOPE_AGENT);
                }
            }
        }
        c2[(size_t)dd * BATCH + bu] = c_reg;
    }
}

// ---------------------------------------------------------------------------
// out[t*64+b] = sigmoid(dot(Wout, h2[t][b][:]) + bout); h2 fp16 [t][b][512]
// ---------------------------------------------------------------------------
__global__ __launch_bounds__(256) void out_kernel(
    const _Float16* __restrict__ h2, const float* __restrict__ Wout,
    const float* __restrict__ bout, float* __restrict__ out)
{
    const int t = blockIdx.x;
    const int q = threadIdx.x >> 6, b = threadIdx.x & 63;
    const _Float16* base = &h2[(size_t)t * HB_STEP + (size_t)b * HDIM];
    float s = 0.0f;
#pragma unroll 8
    for (int k = q * 128; k < q * 128 + 128; k += 4) {
        const uint2 u = *(const uint2*)&base[k];
        f16x4 h = __builtin_bit_cast(f16x4, u);
        s += Wout[k] * (float)h[0] + Wout[k + 1] * (float)h[1]
           + Wout[k + 2] * (float)h[2] + Wout[k + 3] * (float)h[3];
    }
    __shared__ float red[4][64];
    red[q][b] = s;
    __syncthreads();
    if (q == 0) {
        float v = red[0][b] + red[1][b] + red[2][b] + red[3][b] + bout[0];
        out[t * BATCH + b] = sigf(v);
    }
}

// ---------------------------------------------------------------------------
static size_t req_bytes(int C) {
    return 65536                                      // counters
         + 2ull * HDIM * BATCH * 4                    // c1, c2
         + 3ull * GDIM * HDIM * 2                     // Wf1h, Wf2i, Wf2h
         + (size_t)GDIM * INDIM * 2                   // Wf1i
         + (size_t)T_STEPS * BATCH * INDIM * 2        // xh (full sequence)
         + 2ull * (size_t)(C + 1) * BATCH * HDIM * 2; // hb1, hb2
}

extern "C" void kernel_launch(void* const* d_in, const int* in_sizes, int n_in,
                              void* d_out, int out_size, void* d_ws, size_t ws_size,
                              hipStream_t stream)
{
    const float* x    = (const float*)d_in[0];
    const float* Wih1 = (const float*)d_in[1];
    const float* Whh1 = (const float*)d_in[2];
    const float* bih1 = (const float*)d_in[3];
    const float* bhh1 = (const float*)d_in[4];
    const float* Wih2 = (const float*)d_in[5];
    const float* Whh2 = (const float*)d_in[6];
    const float* bih2 = (const float*)d_in[7];
    const float* bhh2 = (const float*)d_in[8];
    const float* Wout = (const float*)d_in[9];
    const float* bout = (const float*)d_in[10];
    float* out = (float*)d_out;

    int C = 8;
    const int cands[] = {2048, 1024, 512, 256, 128, 64, 32, 16, 8};
    for (int i = 0; i < 9; i++)
        if (req_bytes(cands[i]) <= ws_size) { C = cands[i]; break; }

    char* p = (char*)d_ws;
    unsigned*  ctr1  = (unsigned*)p;                p += 32768;
    unsigned*  ctr2  = (unsigned*)p;                p += 32768;
    float*     c1    = (float*)p;                   p += (size_t)HDIM * BATCH * 4;
    float*     c2    = (float*)p;                   p += (size_t)HDIM * BATCH * 4;
    _Float16*  Wf1h  = (_Float16*)p;                p += (size_t)GDIM * HDIM * 2;
    _Float16*  Wf1i  = (_Float16*)p;                p += (size_t)GDIM * INDIM * 2;
    _Float16*  Wf2i  = (_Float16*)p;                p += (size_t)GDIM * HDIM * 2;
    _Float16*  Wf2h  = (_Float16*)p;                p += (size_t)GDIM * HDIM * 2;
    _Float16*  xh    = (_Float16*)p;                p += (size_t)T_STEPS * BATCH * INDIM * 2;
    _Float16*  hb1   = (_Float16*)p;                p += (size_t)(C + 1) * BATCH * HDIM * 2;
    _Float16*  hb2   = (_Float16*)p;

    // zero counters + c-state (contiguous) and the two h carry slots
    hipMemsetAsync(ctr1, 0, 65536 + 2ull * HDIM * BATCH * 4, stream);
    hipMemsetAsync(hb1, 0, (size_t)BATCH * HDIM * 2, stream);
    hipMemsetAsync(hb2, 0, (size_t)BATCH * HDIM * 2, stream);

    // fp16 conversions
    cvt_f16<<<dim3(GDIM * HDIM / 4 / 256), dim3(256), 0, stream>>>(Whh1, Wf1h, GDIM * HDIM / 4);
    cvt_f16<<<dim3(GDIM * INDIM / 4 / 256), dim3(256), 0, stream>>>(Wih1, Wf1i, GDIM * INDIM / 4);
    cvt_f16<<<dim3(GDIM * HDIM / 4 / 256), dim3(256), 0, stream>>>(Wih2, Wf2i, GDIM * HDIM / 4);
    cvt_f16<<<dim3(GDIM * HDIM / 4 / 256), dim3(256), 0, stream>>>(Whh2, Wf2h, GDIM * HDIM / 4);
    cvt_f16<<<dim3(T_STEPS * BATCH * INDIM / 4 / 256), dim3(256), 0, stream>>>(
        x, xh, T_STEPS * BATCH * INDIM / 4);

    const _Float16* h2r = hb2 + (size_t)HB_STEP;   // slots 1..C

    for (int t0 = 0; t0 < T_STEPS; t0 += C) {
        const _Float16* xc = xh + (size_t)t0 * BATCH * INDIM;
        unsigned t0a = (unsigned)t0;
        void* args[] = {(void*)&xc, (void*)&Wf1h, (void*)&Wf1i, (void*)&Wf2i,
                        (void*)&Wf2h, (void*)&bih1, (void*)&bhh1, (void*)&bih2,
                        (void*)&bhh2, (void*)&hb1, (void*)&hb2, (void*)&c1,
                        (void*)&c2, (void*)&ctr1, (void*)&ctr2, (void*)&C,
                        (void*)&t0a};
        hipLaunchCooperativeKernel((void*)lstm_fused, dim3(2 * NBLK_RE), dim3(256),
                                   args, 0, stream);

        out_kernel<<<dim3(C), dim3(256), 0, stream>>>(h2r, Wout, bout,
                                                      out + (size_t)t0 * BATCH);
    }

    (void)in_sizes; (void)n_in; (void)out_size;
}

// Round 8
// 13366.328 us; speedup vs baseline: 1.5089x; 1.5089x over previous
//
#include <hip/hip_runtime.h>
#include <math.h>

#define T_STEPS 2048
#define BATCH   64
#define HDIM    512
#define GDIM    2048   // 4*H
#define INDIM   256
#define NBLK_RE 128    // recurrence workgroups PER LAYER (1 per 4 h-dims)
#define HB_STEP (HDIM * BATCH)   // elements per timestep slot

typedef _Float16 f16x8 __attribute__((ext_vector_type(8)));
typedef _Float16 f16x4 __attribute__((ext_vector_type(4)));
typedef float    f32x4 __attribute__((ext_vector_type(4)));

__device__ __forceinline__ float sigf(float x) { return 1.0f / (1.0f + __expf(-x)); }
__device__ __forceinline__ float tanh_fast(float x) {
    return 1.0f - 2.0f / (__expf(2.0f * x) + 1.0f);   // saturates correctly
}

// ---------------------------------------------------------------------------
// fp32 -> fp16 conversion (weights once per launch; x once, 67 MB)
// ---------------------------------------------------------------------------
__global__ __launch_bounds__(256) void cvt_f16(const float* __restrict__ src,
                                               _Float16* __restrict__ dst, int n4)
{
    int i = blockIdx.x * 256 + threadIdx.x;
    if (i < n4) {
        float4 v = ((const float4*)src)[i];
        f16x4 h;
        h[0] = (_Float16)v.x; h[1] = (_Float16)v.y;
        h[2] = (_Float16)v.z; h[3] = (_Float16)v.w;
        ((f16x4*)dst)[i] = h;
    }
}

// ---------------------------------------------------------------------------
// Partitioned flag poll + LDS epoch exchange. Barrier ladder evidence:
// R7 single line, 1024 waves -> ~1024 req/line  : 9.3 us/step (worst)
// R5 128 lines, all 4 waves poll all             : ~1000 req/line total, 6.0
// This: each wave owns a DISJOINT 32-flag subset -> 256 req/line (/4), and
// cross-wave release is via LDS epochs (ds spin, zero fabric traffic, no
// __syncthreads — R2/R4 showed WG barriers in the wait path cost ~0.5us).
// Ordering: producer drains vmcnt before its flag store (h at LLC); wave
// acquire-fences after seeing its subset, publishes LDS epoch with release;
// other waves acquire the epoch. Consumer h addresses are fresh per step,
// so plain cached h loads cannot hit stale L2 lines (proven R2/R4/R5).
// ---------------------------------------------------------------------------
__device__ __forceinline__ void wait_part(const unsigned* __restrict__ flags,
                                          unsigned tgt, int wv, int ln,
                                          unsigned* eps /* LDS[4] */)
{
    const unsigned* p = flags + (size_t)(wv * 32 + (ln & 31)) * 16;
    unsigned f;
    do {
        f = (ln < 32) ? __hip_atomic_load(p, __ATOMIC_RELAXED,
                                          __HIP_MEMORY_SCOPE_AGENT)
                      : tgt;
    } while (!__all((int)(f >= tgt)));
    __atomic_signal_fence(__ATOMIC_ACQUIRE);
    if (ln == 0)
        __hip_atomic_store(&eps[wv], tgt, __ATOMIC_RELEASE,
                           __HIP_MEMORY_SCOPE_WORKGROUP);
#pragma unroll
    for (int w = 0; w < 4; w++)
        while (__hip_atomic_load(&eps[w], __ATOMIC_ACQUIRE,
                                 __HIP_MEMORY_SCOPE_WORKGROUP) < tgt) {}
}

// ---------------------------------------------------------------------------
// Fully-fused 2-layer MFMA LSTM. 256 WGs: blocks 0..127 = layer 1 (x GEMM
// folded, K=256 fp16), 128..255 = layer 2 (W_ih2@h1 folded, K=512).
// h buffers BATCH-MAJOR [t][b][512]; packed 8B publish via hsm + wave 0
// (round-4 proven). Split MFMA accumulators (round-5). Partitioned poll +
// LDS epochs (new this round).
// ---------------------------------------------------------------------------
__global__ __launch_bounds__(256, 1) void lstm_fused(
    const _Float16* __restrict__ xh,     // [nsteps][64][256] fp16 (batch-major)
    const _Float16* __restrict__ Wf1h,   // W_hh1 [2048][512]
    const _Float16* __restrict__ Wf1i,   // W_ih1 [2048][256]
    const _Float16* __restrict__ Wf2i,   // W_ih2 [2048][512]
    const _Float16* __restrict__ Wf2h,   // W_hh2 [2048][512]
    const float* __restrict__ bih1, const float* __restrict__ bhh1,
    const float* __restrict__ bih2, const float* __restrict__ bhh2,
    _Float16* __restrict__ hb1,          // [nsteps+1][64][512] batch-major
    _Float16* __restrict__ hb2,
    float* __restrict__ c1,              // [512][64]
    float* __restrict__ c2,
    unsigned* __restrict__ flag1,        // [128] @ 64B stride
    unsigned* __restrict__ flag2,
    int nsteps, unsigned t0a)
{
    __shared__ float    gl[16][68];      // gate exchange, padded
    __shared__ _Float16 hsm[64][4];      // packed h per batch
    __shared__ unsigned eps1[4], eps2[4];// per-wave poll epochs

    const int tid   = threadIdx.x;
    const int layer = blockIdx.x >> 7;
    const int wg    = blockIdx.x & (NBLK_RE - 1);
    const int j0    = wg * 4;
    const int wv    = tid >> 6;          // wave = M-tile (16 batches)
    const int ln    = tid & 63;
    const int l16   = ln & 15;
    const int quad  = ln >> 4;
    const int grow  = (l16 >> 2) * HDIM + j0 + (l16 & 3);
    const int du    = wv;                // update thread: dim j0+du, batch bu
    const int bu    = tid & 63;
    const int dd    = j0 + du;

    if (tid < 4) { eps1[tid] = 0u; eps2[tid] = 0u; }
    __syncthreads();

    if (layer == 0) {
        // ------------------------- layer 1 -------------------------
        f16x8 Bh[16], Bx[8];
#pragma unroll
        for (int j = 0; j < 16; j++) {
            const uint4 u = *(const uint4*)&Wf1h[(size_t)grow * HDIM + j * 32 + quad * 8];
            Bh[j] = __builtin_bit_cast(f16x8, u);
        }
#pragma unroll
        for (int j = 0; j < 8; j++) {
            const uint4 u = *(const uint4*)&Wf1i[(size_t)grow * INDIM + j * 32 + quad * 8];
            Bx[j] = __builtin_bit_cast(f16x8, u);
        }
        float c_reg = c1[(size_t)dd * BATCH + bu];
        const float bi_ = bih1[0 * HDIM + dd] + bhh1[0 * HDIM + dd];
        const float bf_ = bih1[1 * HDIM + dd] + bhh1[1 * HDIM + dd];
        const float bg_ = bih1[2 * HDIM + dd] + bhh1[2 * HDIM + dd];
        const float bo_ = bih1[3 * HDIM + dd] + bhh1[3 * HDIM + dd];

        for (int t = 0; t < nsteps; t++) {
            f32x4 ax0 = {0.f, 0.f, 0.f, 0.f}, ax1 = {0.f, 0.f, 0.f, 0.f};

            // --- x contribution first (independent accumulators; no dep) ---
            {
                const _Float16* xp = xh + ((size_t)t * BATCH + 16 * wv + l16) * INDIM
                                   + quad * 8;
                ulonglong2 ax[8];
#pragma unroll
                for (int j = 0; j < 8; j++)
                    ax[j] = *(const ulonglong2*)(xp + j * 32);
#pragma unroll
                for (int j = 0; j < 8; j += 2) {
                    ax0 = __builtin_amdgcn_mfma_f32_16x16x32_f16(
                        __builtin_bit_cast(f16x8, ax[j]),     Bx[j],     ax0, 0, 0, 0);
                    ax1 = __builtin_amdgcn_mfma_f32_16x16x32_f16(
                        __builtin_bit_cast(f16x8, ax[j + 1]), Bx[j + 1], ax1, 0, 0, 0);
                }
            }

            // --- critical path: W_hh1 @ h1[t] (fresh accumulator chains) ---
            wait_part(flag1, t0a + (unsigned)t, wv, ln, eps1);
            f32x4 ah0 = {0.f, 0.f, 0.f, 0.f}, ah1 = {0.f, 0.f, 0.f, 0.f};
            f32x4 ah2 = {0.f, 0.f, 0.f, 0.f}, ah3 = {0.f, 0.f, 0.f, 0.f};
            {
                const _Float16* hp = hb1 + (size_t)t * HB_STEP
                                   + (size_t)(16 * wv + l16) * HDIM + quad * 8;
                ulonglong2 a[16];
#pragma unroll
                for (int j = 0; j < 16; j++)
                    a[j] = *(const ulonglong2*)(hp + j * 32);
#pragma unroll
                for (int j = 0; j < 16; j += 4) {
                    ah0 = __builtin_amdgcn_mfma_f32_16x16x32_f16(
                        __builtin_bit_cast(f16x8, a[j]),     Bh[j],     ah0, 0, 0, 0);
                    ah1 = __builtin_amdgcn_mfma_f32_16x16x32_f16(
                        __builtin_bit_cast(f16x8, a[j + 1]), Bh[j + 1], ah1, 0, 0, 0);
                    ah2 = __builtin_amdgcn_mfma_f32_16x16x32_f16(
                        __builtin_bit_cast(f16x8, a[j + 2]), Bh[j + 2], ah2, 0, 0, 0);
                    ah3 = __builtin_amdgcn_mfma_f32_16x16x32_f16(
                        __builtin_bit_cast(f16x8, a[j + 3]), Bh[j + 3], ah3, 0, 0, 0);
                }
            }
            f32x4 d = (ax0 + ax1) + ((ah0 + ah1) + (ah2 + ah3));
            *(f32x4*)&gl[l16][16 * wv + quad * 4] = d;
            __syncthreads();

            {
                float si = gl[4 * 0 + du][bu] + bi_;
                float sf = gl[4 * 1 + du][bu] + bf_;
                float sg = gl[4 * 2 + du][bu] + bg_;
                float so = gl[4 * 3 + du][bu] + bo_;
                c_reg = sigf(sf) * c_reg + sigf(si) * tanh_fast(sg);
                float h = sigf(so) * tanh_fast(c_reg);
                hsm[bu][du] = (_Float16)h;
            }
            __syncthreads();   // hsm ready; also protects gl before next D-write

            // --- packed publish (wave 0): one 8B quad per batch ---
            if (tid < 64) {
                unsigned long long pk = *(const unsigned long long*)&hsm[tid][0];
                unsigned long long* dst = (unsigned long long*)
                    (hb1 + (size_t)(t + 1) * HB_STEP + (size_t)tid * HDIM + j0);
                __hip_atomic_store(dst, pk, __ATOMIC_RELAXED, __HIP_MEMORY_SCOPE_AGENT);
                if (t == nsteps - 1) {   // carry slot for next chunk
                    unsigned long long* dst0 = (unsigned long long*)
                        (hb1 + (size_t)tid * HDIM + j0);
                    __hip_atomic_store(dst0, pk, __ATOMIC_RELAXED, __HIP_MEMORY_SCOPE_AGENT);
                }
                if (tid == 0) {
                    asm volatile("s_waitcnt vmcnt(0)" ::: "memory");  // h at LLC
                    __hip_atomic_store(flag1 + (size_t)wg * 16, t0a + (unsigned)t + 1u,
                                       __ATOMIC_RELAXED, __HIP_MEMORY_SCOPE_AGENT);
                }
            }
        }
        c1[(size_t)dd * BATCH + bu] = c_reg;
    } else {
        // ------------------------- layer 2 -------------------------
        f16x8 Bh[16], Bi[16];
#pragma unroll
        for (int j = 0; j < 16; j++) {
            const uint4 uh = *(const uint4*)&Wf2h[(size_t)grow * HDIM + j * 32 + quad * 8];
            Bh[j] = __builtin_bit_cast(f16x8, uh);
            const uint4 ui = *(const uint4*)&Wf2i[(size_t)grow * HDIM + j * 32 + quad * 8];
            Bi[j] = __builtin_bit_cast(f16x8, ui);
        }
        float c_reg = c2[(size_t)dd * BATCH + bu];
        const float bi_ = bih2[0 * HDIM + dd] + bhh2[0 * HDIM + dd];
        const float bf_ = bih2[1 * HDIM + dd] + bhh2[1 * HDIM + dd];
        const float bg_ = bih2[2 * HDIM + dd] + bhh2[2 * HDIM + dd];
        const float bo_ = bih2[3 * HDIM + dd] + bhh2[3 * HDIM + dd];

        for (int t = 0; t < nsteps; t++) {
            f32x4 ai0 = {0.f, 0.f, 0.f, 0.f}, ai1 = {0.f, 0.f, 0.f, 0.f};
            f32x4 ag0 = {0.f, 0.f, 0.f, 0.f}, ag1 = {0.f, 0.f, 0.f, 0.f};

            // --- W_ih2 @ h1[t+1] (independent accumulators) ---
            wait_part(flag1, t0a + (unsigned)t + 1u, wv, ln, eps1);
            {
                const _Float16* hp = hb1 + (size_t)(t + 1) * HB_STEP
                                   + (size_t)(16 * wv + l16) * HDIM + quad * 8;
                ulonglong2 a[16];
#pragma unroll
                for (int j = 0; j < 16; j++)
                    a[j] = *(const ulonglong2*)(hp + j * 32);
#pragma unroll
                for (int j = 0; j < 16; j += 2) {
                    ai0 = __builtin_amdgcn_mfma_f32_16x16x32_f16(
                        __builtin_bit_cast(f16x8, a[j]),     Bi[j],     ai0, 0, 0, 0);
                    ai1 = __builtin_amdgcn_mfma_f32_16x16x32_f16(
                        __builtin_bit_cast(f16x8, a[j + 1]), Bi[j + 1], ai1, 0, 0, 0);
                }
            }

            // --- critical path: W_hh2 @ h2[t] ---
            wait_part(flag2, t0a + (unsigned)t, wv, ln, eps2);
            {
                const _Float16* hp = hb2 + (size_t)t * HB_STEP
                                   + (size_t)(16 * wv + l16) * HDIM + quad * 8;
                ulonglong2 a[16];
#pragma unroll
                for (int j = 0; j < 16; j++)
                    a[j] = *(const ulonglong2*)(hp + j * 32);
#pragma unroll
                for (int j = 0; j < 16; j += 2) {
                    ag0 = __builtin_amdgcn_mfma_f32_16x16x32_f16(
                        __builtin_bit_cast(f16x8, a[j]),     Bh[j],     ag0, 0, 0, 0);
                    ag1 = __builtin_amdgcn_mfma_f32_16x16x32_f16(
                        __builtin_bit_cast(f16x8, a[j + 1]), Bh[j + 1], ag1, 0, 0, 0);
                }
            }
            f32x4 d = (ai0 + ai1) + (ag0 + ag1);
            *(f32x4*)&gl[l16][16 * wv + quad * 4] = d;
            __syncthreads();

            {
                float si = gl[4 * 0 + du][bu] + bi_;
                float sf = gl[4 * 1 + du][bu] + bf_;
                float sg = gl[4 * 2 + du][bu] + bg_;
                float so = gl[4 * 3 + du][bu] + bo_;
                c_reg = sigf(sf) * c_reg + sigf(si) * tanh_fast(sg);
                float h = sigf(so) * tanh_fast(c_reg);
                hsm[bu][du] = (_Float16)h;
            }
            __syncthreads();

            if (tid < 64) {
                unsigned long long pk = *(const unsigned long long*)&hsm[tid][0];
                unsigned long long* dst = (unsigned long long*)
                    (hb2 + (size_t)(t + 1) * HB_STEP + (size_t)tid * HDIM + j0);
                __hip_atomic_store(dst, pk, __ATOMIC_RELAXED, __HIP_MEMORY_SCOPE_AGENT);
                if (t == nsteps - 1) {
                    unsigned long long* dst0 = (unsigned long long*)
                        (hb2 + (size_t)tid * HDIM + j0);
                    __hip_atomic_store(dst0, pk, __ATOMIC_RELAXED, __HIP_MEMORY_SCOPE_AGENT);
                }
                if (tid == 0) {
                    asm volatile("s_waitcnt vmcnt(0)" ::: "memory");
                    __hip_atomic_store(flag2 + (size_t)wg * 16, t0a + (unsigned)t + 1u,
                                       __ATOMIC_RELAXED, __HIP_MEMORY_SCOPE_AGENT);
                }
            }
        }
        c2[(size_t)dd * BATCH + bu] = c_reg;
    }
}

// ---------------------------------------------------------------------------
// out[t*64+b] = sigmoid(dot(Wout, h2[t][b][:]) + bout); h2 fp16 [t][b][512]
// ---------------------------------------------------------------------------
__global__ __launch_bounds__(256) void out_kernel(
    const _Float16* __restrict__ h2, const float* __restrict__ Wout,
    const float* __restrict__ bout, float* __restrict__ out)
{
    const int t = blockIdx.x;
    const int q = threadIdx.x >> 6, b = threadIdx.x & 63;
    const _Float16* base = &h2[(size_t)t * HB_STEP + (size_t)b * HDIM];
    float s = 0.0f;
#pragma unroll 8
    for (int k = q * 128; k < q * 128 + 128; k += 4) {
        const uint2 u = *(const uint2*)&base[k];
        f16x4 h = __builtin_bit_cast(f16x4, u);
        s += Wout[k] * (float)h[0] + Wout[k + 1] * (float)h[1]
           + Wout[k + 2] * (float)h[2] + Wout[k + 3] * (float)h[3];
    }
    __shared__ float red[4][64];
    red[q][b] = s;
    __syncthreads();
    if (q == 0) {
        float v = red[0][b] + red[1][b] + red[2][b] + red[3][b] + bout[0];
        out[t * BATCH + b] = sigf(v);
    }
}

// ---------------------------------------------------------------------------
static size_t req_bytes(int C) {
    return 65536                                      // flag arrays
         + 2ull * HDIM * BATCH * 4                    // c1, c2
         + 3ull * GDIM * HDIM * 2                     // Wf1h, Wf2i, Wf2h
         + (size_t)GDIM * INDIM * 2                   // Wf1i
         + (size_t)T_STEPS * BATCH * INDIM * 2        // xh (full sequence)
         + 2ull * (size_t)(C + 1) * BATCH * HDIM * 2; // hb1, hb2
}

extern "C" void kernel_launch(void* const* d_in, const int* in_sizes, int n_in,
                              void* d_out, int out_size, void* d_ws, size_t ws_size,
                              hipStream_t stream)
{
    const float* x    = (const float*)d_in[0];
    const float* Wih1 = (const float*)d_in[1];
    const float* Whh1 = (const float*)d_in[2];
    const float* bih1 = (const float*)d_in[3];
    const float* bhh1 = (const float*)d_in[4];
    const float* Wih2 = (const float*)d_in[5];
    const float* Whh2 = (const float*)d_in[6];
    const float* bih2 = (const float*)d_in[7];
    const float* bhh2 = (const float*)d_in[8];
    const float* Wout = (const float*)d_in[9];
    const float* bout = (const float*)d_in[10];
    float* out = (float*)d_out;

    int C = 8;
    const int cands[] = {2048, 1024, 512, 256, 128, 64, 32, 16, 8};
    for (int i = 0; i < 9; i++)
        if (req_bytes(cands[i]) <= ws_size) { C = cands[i]; break; }

    char* p = (char*)d_ws;
    unsigned*  flag1 = (unsigned*)p;                p += 32768;
    unsigned*  flag2 = (unsigned*)p;                p += 32768;
    float*     c1    = (float*)p;                   p += (size_t)HDIM * BATCH * 4;
    float*     c2    = (float*)p;                   p += (size_t)HDIM * BATCH * 4;
    _Float16*  Wf1h  = (_Float16*)p;                p += (size_t)GDIM * HDIM * 2;
    _Float16*  Wf1i  = (_Float16*)p;                p += (size_t)GDIM * INDIM * 2;
    _Float16*  Wf2i  = (_Float16*)p;                p += (size_t)GDIM * HDIM * 2;
    _Float16*  Wf2h  = (_Float16*)p;                p += (size_t)GDIM * HDIM * 2;
    _Float16*  xh    = (_Float16*)p;                p += (size_t)T_STEPS * BATCH * INDIM * 2;
    _Float16*  hb1   = (_Float16*)p;                p += (size_t)(C + 1) * BATCH * HDIM * 2;
    _Float16*  hb2   = (_Float16*)p;

    // zero flags + c-state (contiguous) and the two h carry slots
    hipMemsetAsync(flag1, 0, 65536 + 2ull * HDIM * BATCH * 4, stream);
    hipMemsetAsync(hb1, 0, (size_t)BATCH * HDIM * 2, stream);
    hipMemsetAsync(hb2, 0, (size_t)BATCH * HDIM * 2, stream);

    // fp16 conversions
    cvt_f16<<<dim3(GDIM * HDIM / 4 / 256), dim3(256), 0, stream>>>(Whh1, Wf1h, GDIM * HDIM / 4);
    cvt_f16<<<dim3(GDIM * INDIM / 4 / 256), dim3(256), 0, stream>>>(Wih1, Wf1i, GDIM * INDIM / 4);
    cvt_f16<<<dim3(GDIM * HDIM / 4 / 256), dim3(256), 0, stream>>>(Wih2, Wf2i, GDIM * HDIM / 4);
    cvt_f16<<<dim3(GDIM * HDIM / 4 / 256), dim3(256), 0, stream>>>(Whh2, Wf2h, GDIM * HDIM / 4);
    cvt_f16<<<dim3(T_STEPS * BATCH * INDIM / 4 / 256), dim3(256), 0, stream>>>(
        x, xh, T_STEPS * BATCH * INDIM / 4);

    const _Float16* h2r = hb2 + (size_t)HB_STEP;   // slots 1..C

    for (int t0 = 0; t0 < T_STEPS; t0 += C) {
        const _Float16* xc = xh + (size_t)t0 * BATCH * INDIM;
        unsigned t0a = (unsigned)t0;
        void* args[] = {(void*)&xc, (void*)&Wf1h, (void*)&Wf1i, (void*)&Wf2i,
                        (void*)&Wf2h, (void*)&bih1, (void*)&bhh1, (void*)&bih2,
                        (void*)&bhh2, (void*)&hb1, (void*)&hb2, (void*)&c1,
                        (void*)&c2, (void*)&flag1, (void*)&flag2, (void*)&C,
                        (void*)&t0a};
        hipLaunchCooperativeKernel((void*)lstm_fused, dim3(2 * NBLK_RE), dim3(256),
                                   args, 0, stream);

        out_kernel<<<dim3(C), dim3(256), 0, stream>>>(h2r, Wout, bout,
                                                      out + (size_t)t0 * BATCH);
    }

    (void)in_sizes; (void)n_in; (void)out_size;
}